// Round 2
// baseline (254.843 us; speedup 1.0000x reference)
//
#include <hip/hip_runtime.h>
#include <math.h>

#define N_NODES 100000
#define N_EDGES 1600000
#define NB_BANK 1000
#define N_PAIRS 500000

#define BUCK_SHIFT 9
#define BUCK_NODES 512
#define NBUCK 196            // ceil(N_NODES/512)
#define BCAP 10240           // fixed ebuf/csr stride per bucket (mean 8163 + 22 sigma)
#define EPB 4096             // edges per scatter block (392 blocks: 1.5/CU)
#define NSCAT 391            // ceil(N_EDGES/EPB)
#define NZBLK 1954           // ceil(N_PAIRS/256)
#define SMASK 0x1FFFF        // low 17 bits = src id (N_NODES < 2^17)

typedef __attribute__((ext_vector_type(4))) float f4raw;  // nontemporal-able

struct Consts {
  float C[27*8];    // [P1|P2] : X -> 8 channels
  float Rb[27*8];   // [Wb@Ttop | Wb@Tbot]
  float u[8];       // coefficient of dvec (A-hat * 1)
  float vg[8];      // graph-row constant
  float vb[8];      // bank-row constant
};

// ---- dense weight-chain precompute, runs as the extra block of k_scatter ----
__device__ void precompute_body(
    const float* __restrict__ W1, const float* __restrict__ b1,
    const float* __restrict__ W2, const float* __restrict__ b2,
    const float* __restrict__ Wb, const float* __restrict__ bb,
    const float* __restrict__ Wf1, const float* __restrict__ bf1,
    const float* __restrict__ Wf2, const float* __restrict__ bf2,
    const float* __restrict__ Wf3, const float* __restrict__ bf3,
    Consts* __restrict__ cst) {
  __shared__ float A[40*4];    // Wf2 @ Wf3
  __shared__ float T[100*4];   // Wf1 @ A
  __shared__ float B[60*8];    // W2 @ [Ttop|Tbot]
  __shared__ float cvec[4];
  const int tid = threadIdx.x;
  const int nt = blockDim.x;

  for (int idx = tid; idx < 160; idx += nt) {
    int r = idx >> 2, k = idx & 3;
    float s = 0.f;
    for (int j = 0; j < 20; ++j) s += Wf2[r*20+j] * Wf3[j*4+k];
    A[idx] = s;
  }
  __syncthreads();
  for (int idx = tid; idx < 400; idx += nt) {
    int r = idx >> 2, k = idx & 3;
    float s = 0.f;
    for (int j = 0; j < 40; ++j) s += Wf1[r*40+j] * A[j*4+k];
    T[idx] = s;
  }
  if (tid < 4) {
    float s = bf3[tid];
    for (int j = 0; j < 40; ++j) s += bf1[j] * A[j*4+tid];
    for (int j = 0; j < 20; ++j) s += bf2[j] * Wf3[j*4+tid];
    cvec[tid] = s;
  }
  __syncthreads();
  for (int idx = tid; idx < 480; idx += nt) {
    int r = idx >> 3, k = idx & 7;
    int half = k >> 2, kk = k & 3;
    float s = 0.f;
    for (int j = 0; j < 50; ++j) s += W2[r*50+j] * T[(half*50+j)*4+kk];
    B[idx] = s;
  }
  __syncthreads();
  for (int idx = tid; idx < 456; idx += nt) {
    if (idx < 216) {                       // C = W1 @ B [27,8]
      int r = idx >> 3, k = idx & 7;
      float s = 0.f;
      for (int j = 0; j < 60; ++j) s += W1[r*60+j] * B[j*8+k];
      cst->C[idx] = s;
    } else if (idx < 432) {                // Rb = Wb @ [Ttop|Tbot] [27,8]
      int i2 = idx - 216;
      int r = i2 >> 3, k = i2 & 7, half = k >> 2, kk = k & 3;
      float s = 0.f;
      for (int j = 0; j < 50; ++j) s += Wb[r*50+j] * T[(half*50+j)*4+kk];
      cst->Rb[i2] = s;
    } else if (idx < 440) {                // u = b1 @ B
      int k = idx - 432;
      float s = 0.f;
      for (int j = 0; j < 60; ++j) s += b1[j] * B[j*8+k];
      cst->u[k] = s;
    } else if (idx < 448) {                // vg = b2 @ [Ttop|Tbot] (+c on half 0)
      int k = idx - 440, half = k >> 2, kk = k & 3;
      float s = (half == 0) ? cvec[kk] : 0.f;
      for (int j = 0; j < 50; ++j) s += b2[j] * T[(half*50+j)*4+kk];
      cst->vg[k] = s;
    } else {                               // vb = bb @ [Ttop|Tbot] (+c on half 0)
      int k = idx - 448, half = k >> 2, kk = k & 3;
      float s = (half == 0) ? cvec[kk] : 0.f;
      for (int j = 0; j < 50; ++j) s += bb[j] * T[(half*50+j)*4+kk];
      cst->vb[k] = s;
    }
  }
}

// --- single-pass bucket scatter into fixed-stride ebuf; bcnt[b] -> counts ----
// dst ids register-cached across the two passes; extra block runs precompute.
__global__ __launch_bounds__(1024) void k_scatter(
    const int* __restrict__ ei, int* __restrict__ bcnt, int* __restrict__ ebuf,
    const float* __restrict__ W1, const float* __restrict__ b1,
    const float* __restrict__ W2, const float* __restrict__ b2,
    const float* __restrict__ Wb, const float* __restrict__ bb,
    const float* __restrict__ Wf1, const float* __restrict__ bf1,
    const float* __restrict__ Wf2, const float* __restrict__ bf2,
    const float* __restrict__ Wf3, const float* __restrict__ bf3,
    Consts* __restrict__ cst) {
  if (blockIdx.x == NSCAT) {   // whole-block branch: safe with __syncthreads
    precompute_body(W1, b1, W2, b2, Wb, bb, Wf1, bf1, Wf2, bf2, Wf3, bf3, cst);
    return;
  }
  __shared__ int hist[NBUCK];
  __shared__ int base[NBUCK];
  const int t = threadIdx.x;
  const int e0 = blockIdx.x * EPB;
  int dcache[EPB / 1024];
  if (t < NBUCK) hist[t] = 0;
  __syncthreads();
#pragma unroll
  for (int i = 0; i < EPB / 1024; ++i) {
    int e = e0 + i * 1024 + t;
    int d = -1;
    if (e < N_EDGES) d = __builtin_nontemporal_load(&ei[N_EDGES + e]);
    dcache[i] = d;
    if (d >= 0) atomicAdd(&hist[d >> BUCK_SHIFT], 1);
  }
  __syncthreads();
  if (t < NBUCK) {
    int h = hist[t];
    base[t] = h ? (t * BCAP + atomicAdd(&bcnt[t], h)) : 0;
    hist[t] = 0;
  }
  __syncthreads();
#pragma unroll
  for (int i = 0; i < EPB / 1024; ++i) {
    int e = e0 + i * 1024 + t;
    int d = dcache[i];
    if (d >= 0) {
      int s = __builtin_nontemporal_load(&ei[e]);
      int b = d >> BUCK_SHIFT;
      int pos = base[b] + atomicAdd(&hist[b], 1);
      ebuf[pos] = ((d & (BUCK_NODES - 1)) << 17) | s;
    }
  }
}

// -- per-bucket: degree -> dinv + rbeg/rend, CSR fill, AND fused Xs compute ---
// (k_x8 folded in: this block owns exactly the 512 nodes whose dinv it just
//  computed; x rows staged in LDS. Also writes the zero pad row at N_NODES
//  used by the masked gather batches.)
__global__ __launch_bounds__(1024) void k_degfill_x8(
    const int* __restrict__ bcnt, const int* __restrict__ ebuf,
    const float* __restrict__ x, const Consts* __restrict__ cst,
    float* __restrict__ dinv, int* __restrict__ rbeg, int* __restrict__ rend,
    int* __restrict__ csr, float* __restrict__ Xs) {
  __shared__ int cnt[BUCK_NODES];
  __shared__ int lcur[BUCK_NODES];
  __shared__ float sdinv[BUCK_NODES];
  __shared__ float xs[BUCK_NODES * 27];     // 55.3 KB (total ~60 KB < 64 KB)
  const int b = blockIdx.x;
  const int t = threadIdx.x;
  if (t < BUCK_NODES) cnt[t] = 0;
  __syncthreads();
  const int beg = b * BCAP, end = beg + bcnt[b];
  for (int j = beg + t; j < end; j += 1024)
    atomicAdd(&cnt[ebuf[j] >> 17], 1);
  // stage x rows for this bucket (independent work, overlaps count pass)
  const int xbase = b * (BUCK_NODES * 27);
  for (int j = t; j < BUCK_NODES * 27; j += 1024) {
    int g = xbase + j;
    xs[j] = (g < N_NODES * 27) ? __builtin_nontemporal_load(&x[g]) : 0.f;
  }
  __syncthreads();
  int v = (t < BUCK_NODES) ? cnt[t] : 0;
  // Hillis-Steele inclusive scan over 512 (threads >=512 idle but hit barriers)
  for (int off = 1; off < BUCK_NODES; off <<= 1) {
    int u = (t < BUCK_NODES && t >= off) ? cnt[t - off] : 0;
    __syncthreads();
    if (t < BUCK_NODES) cnt[t] += u;
    __syncthreads();
  }
  if (t < BUCK_NODES) {
    const int node = (b << BUCK_SHIFT) + t;
    const int excl = beg + cnt[t] - v;   // start within this bucket's csr range
    lcur[t] = excl;
    float dv = (node < N_NODES) ? rsqrtf((float)v + 1.0f) : 0.f;
    sdinv[t] = dv;
    if (node < N_NODES) {
      rbeg[node] = excl;
      rend[node] = excl + v;
      dinv[node] = dv;
    } else if (node == N_NODES) {
      dinv[node] = 0.f;                  // pad row for masked gathers
    }
  }
  __syncthreads();
  for (int j = beg + t; j < end; j += 1024) {
    int code = ebuf[j];
    int pos = atomicAdd(&lcur[code >> 17], 1);
    csr[pos] = code & SMASK;
  }
  // fused Xs = (x @ C) * dinv for this bucket's 512 nodes (+ zero pad row)
  for (int idx = t; idx < BUCK_NODES * 8; idx += 1024) {
    int li = idx >> 3, k = idx & 7;
    int node = (b << BUCK_SHIFT) + li;
    if (node <= N_NODES) {               // node==N_NODES: xs row + sdinv are 0
      float s = 0.f;
      for (int c = 0; c < 27; ++c) s += xs[li*27+c] * cst->C[c*8+k];
      Xs[(size_t)node*8+k] = s * sdinv[li];
    }
  }
}

// ------ gather pass 1: 4-lane teams (2 channel-halves x 2 row-halves) --------
// Fully-masked unroll-8 batches: OOB lanes clamp into csr and redirect the
// payload to the zero pad row N_NODES -> no serial dependent-chain tail.
__global__ __launch_bounds__(256) void k_gather1(
    const int* __restrict__ rbeg, const int* __restrict__ rend,
    const int* __restrict__ csr, const float* __restrict__ dinv,
    const float4* __restrict__ Xs4, float4* __restrict__ Ys4,
    float* __restrict__ dvec) {
  int t = blockIdx.x * 256 + threadIdx.x;
  int d = t >> 2;
  if (d > N_NODES) return;
  int q = t & 1, r = (t >> 1) & 1;       // q: channel half, r: row half
  if (d == N_NODES) {                    // zero pad row for pass-2 masking
    if (r == 0) Ys4[(size_t)d*2+q] = make_float4(0.f, 0.f, 0.f, 0.f);
    return;
  }
  const int beg = rbeg[d], end = rend[d], e1 = end - 1;
  const float nd = dinv[d];
  float ax = 0.f, ay = 0.f, az = 0.f, aw = 0.f, dsum = 0.f;
  for (int j = beg + r; j < end; j += 16) {   // this lane: stride-2 edges
    int k1 = j+2, k2 = j+4, k3 = j+6, k4 = j+8, k5 = j+10, k6 = j+12, k7 = j+14;
    int c0 = __builtin_nontemporal_load(&csr[j]);
    int c1 = __builtin_nontemporal_load(&csr[k1 < e1 ? k1 : e1]);
    int c2 = __builtin_nontemporal_load(&csr[k2 < e1 ? k2 : e1]);
    int c3 = __builtin_nontemporal_load(&csr[k3 < e1 ? k3 : e1]);
    int c4 = __builtin_nontemporal_load(&csr[k4 < e1 ? k4 : e1]);
    int c5 = __builtin_nontemporal_load(&csr[k5 < e1 ? k5 : e1]);
    int c6 = __builtin_nontemporal_load(&csr[k6 < e1 ? k6 : e1]);
    int c7 = __builtin_nontemporal_load(&csr[k7 < e1 ? k7 : e1]);
    int s0 = c0;
    int s1 = (k1 < end) ? c1 : N_NODES;
    int s2 = (k2 < end) ? c2 : N_NODES;
    int s3 = (k3 < end) ? c3 : N_NODES;
    int s4 = (k4 < end) ? c4 : N_NODES;
    int s5 = (k5 < end) ? c5 : N_NODES;
    int s6 = (k6 < end) ? c6 : N_NODES;
    int s7 = (k7 < end) ? c7 : N_NODES;
    float4 a0 = Xs4[(size_t)s0*2+q], a1 = Xs4[(size_t)s1*2+q];
    float4 a2 = Xs4[(size_t)s2*2+q], a3 = Xs4[(size_t)s3*2+q];
    float4 a4 = Xs4[(size_t)s4*2+q], a5 = Xs4[(size_t)s5*2+q];
    float4 a6 = Xs4[(size_t)s6*2+q], a7 = Xs4[(size_t)s7*2+q];
    ax += ((a0.x+a1.x)+(a2.x+a3.x)) + ((a4.x+a5.x)+(a6.x+a7.x));
    ay += ((a0.y+a1.y)+(a2.y+a3.y)) + ((a4.y+a5.y)+(a6.y+a7.y));
    az += ((a0.z+a1.z)+(a2.z+a3.z)) + ((a4.z+a5.z)+(a6.z+a7.z));
    aw += ((a0.w+a1.w)+(a2.w+a3.w)) + ((a4.w+a5.w)+(a6.w+a7.w));
    if (q == 0)
      dsum += ((dinv[s0]+dinv[s1]) + (dinv[s2]+dinv[s3]))
            + ((dinv[s4]+dinv[s5]) + (dinv[s6]+dinv[s7]));
  }
  // combine the two row-halves (lanes differing in bit 1)
  ax += __shfl_xor(ax, 2); ay += __shfl_xor(ay, 2);
  az += __shfl_xor(az, 2); aw += __shfl_xor(aw, 2);
  if (q == 0) dsum += __shfl_xor(dsum, 2);
  if (r == 0) {
    float4 self = Xs4[(size_t)d*2+q];
    float nn = nd * nd;
    Ys4[(size_t)d*2+q] = make_float4(nn*(ax+self.x), nn*(ay+self.y),
                                     nn*(az+self.z), nn*(aw+self.w));
    if (q == 0) dvec[d] = nd * (dsum + nd);   // +nd = self-loop term
  }
}

// ------ gather pass 2 (+bank rows): gall = nd(sum+self) + dvec*u + vg --------
__global__ __launch_bounds__(256) void k_gather2g(
    const int* __restrict__ rbeg, const int* __restrict__ rend,
    const int* __restrict__ csr, const float* __restrict__ dinv,
    const float4* __restrict__ Ys4, const float* __restrict__ dvec,
    const float* __restrict__ bank, const Consts* __restrict__ cst,
    float4* __restrict__ gall4) {
  int t = blockIdx.x * 256 + threadIdx.x;
  int d = t >> 2;
  if (d >= N_NODES + NB_BANK) return;
  int q = t & 1, r = (t >> 1) & 1;
  if (d >= N_NODES) {                    // bank rows: r==0 lanes only
    if (r) return;
    int bk = d - N_NODES;
    int c0 = 4*q;
    float sa = cst->vb[c0],   sb = cst->vb[c0+1];
    float sc = cst->vb[c0+2], sd = cst->vb[c0+3];
    for (int cc = 0; cc < 27; ++cc) {
      float bv = bank[bk*27+cc];
      sa += bv * cst->Rb[cc*8+c0];
      sb += bv * cst->Rb[cc*8+c0+1];
      sc += bv * cst->Rb[cc*8+c0+2];
      sd += bv * cst->Rb[cc*8+c0+3];
    }
    gall4[(size_t)d*2+q] = make_float4(sa, sb, sc, sd);
    return;
  }
  const int beg = rbeg[d], end = rend[d], e1 = end - 1;
  float ax = 0.f, ay = 0.f, az = 0.f, aw = 0.f;
  for (int j = beg + r; j < end; j += 16) {
    int k1 = j+2, k2 = j+4, k3 = j+6, k4 = j+8, k5 = j+10, k6 = j+12, k7 = j+14;
    int c0 = __builtin_nontemporal_load(&csr[j]);
    int c1 = __builtin_nontemporal_load(&csr[k1 < e1 ? k1 : e1]);
    int c2 = __builtin_nontemporal_load(&csr[k2 < e1 ? k2 : e1]);
    int c3 = __builtin_nontemporal_load(&csr[k3 < e1 ? k3 : e1]);
    int c4 = __builtin_nontemporal_load(&csr[k4 < e1 ? k4 : e1]);
    int c5 = __builtin_nontemporal_load(&csr[k5 < e1 ? k5 : e1]);
    int c6 = __builtin_nontemporal_load(&csr[k6 < e1 ? k6 : e1]);
    int c7 = __builtin_nontemporal_load(&csr[k7 < e1 ? k7 : e1]);
    int s0 = c0;
    int s1 = (k1 < end) ? c1 : N_NODES;
    int s2 = (k2 < end) ? c2 : N_NODES;
    int s3 = (k3 < end) ? c3 : N_NODES;
    int s4 = (k4 < end) ? c4 : N_NODES;
    int s5 = (k5 < end) ? c5 : N_NODES;
    int s6 = (k6 < end) ? c6 : N_NODES;
    int s7 = (k7 < end) ? c7 : N_NODES;
    float4 a0 = Ys4[(size_t)s0*2+q], a1 = Ys4[(size_t)s1*2+q];
    float4 a2 = Ys4[(size_t)s2*2+q], a3 = Ys4[(size_t)s3*2+q];
    float4 a4 = Ys4[(size_t)s4*2+q], a5 = Ys4[(size_t)s5*2+q];
    float4 a6 = Ys4[(size_t)s6*2+q], a7 = Ys4[(size_t)s7*2+q];
    ax += ((a0.x+a1.x)+(a2.x+a3.x)) + ((a4.x+a5.x)+(a6.x+a7.x));
    ay += ((a0.y+a1.y)+(a2.y+a3.y)) + ((a4.y+a5.y)+(a6.y+a7.y));
    az += ((a0.z+a1.z)+(a2.z+a3.z)) + ((a4.z+a5.z)+(a6.z+a7.z));
    aw += ((a0.w+a1.w)+(a2.w+a3.w)) + ((a4.w+a5.w)+(a6.w+a7.w));
  }
  ax += __shfl_xor(ax, 2); ay += __shfl_xor(ay, 2);
  az += __shfl_xor(az, 2); aw += __shfl_xor(aw, 2);
  if (r == 0) {
    float4 self = Ys4[(size_t)d*2+q];
    float nd = dinv[d], dv = dvec[d];
    int c0 = 4*q;
    gall4[(size_t)d*2+q] = make_float4(
        nd*(ax+self.x) + dv*cst->u[c0]   + cst->vg[c0],
        nd*(ay+self.y) + dv*cst->u[c0+1] + cst->vg[c0+1],
        nd*(az+self.z) + dv*cst->u[c0+2] + cst->vg[c0+2],
        nd*(aw+self.w) + dv*cst->u[c0+3] + cst->vg[c0+3]);
  }
}

// ---------------- online-softmax merge helper --------------------------------
__device__ inline void sm_merge(float4& m1, float4& s1,
                                const float4 m2, const float4 s2) {
  float4 M;
  M.x = fmaxf(m1.x, m2.x); M.y = fmaxf(m1.y, m2.y);
  M.z = fmaxf(m1.z, m2.z); M.w = fmaxf(m1.w, m2.w);
  s1.x = s1.x * expf(m1.x - M.x) + s2.x * expf(m2.x - M.x);
  s1.y = s1.y * expf(m1.y - M.y) + s2.y * expf(m2.y - M.y);
  s1.z = s1.z * expf(m1.z - M.z) + s2.z * expf(m2.z - M.z);
  s1.w = s1.w * expf(m1.w - M.w) + s2.w * expf(m2.w - M.w);
  m1 = M;
}

// ---- pair gather + z + block stats; LAST block combines -> gms (no k_comb) --
__global__ __launch_bounds__(256) void k_z(const int* __restrict__ node1,
                                           const int* __restrict__ node2,
                                           const float* __restrict__ gall,
                                           float* __restrict__ z,
                                           float4* __restrict__ bs_m,
                                           float4* __restrict__ bs_s,
                                           int* __restrict__ ticket,
                                           float* __restrict__ gms) {
  int p = blockIdx.x * 256 + threadIdx.x;
  float4 m = make_float4(-1e30f, -1e30f, -1e30f, -1e30f);
  float4 s = make_float4(0.f, 0.f, 0.f, 0.f);
  if (p < N_PAIRS) {
    int n1 = __builtin_nontemporal_load(&node1[p]);
    int n2 = __builtin_nontemporal_load(&node2[p]);
    const float4 a = *(const float4*)(gall + (size_t)n1*8);
    const float4 b = *(const float4*)(gall + (size_t)n2*8 + 4);
    float4 zv = make_float4(a.x+b.x, a.y+b.y, a.z+b.z, a.w+b.w);
    f4raw zr = {zv.x, zv.y, zv.z, zv.w};
    __builtin_nontemporal_store(zr, (f4raw*)z + p);   // stream, keep gall hot
    m = zv; s = make_float4(1.f, 1.f, 1.f, 1.f);
  }
  __shared__ float4 lm[256], ls[256];
  __shared__ int islast;
  lm[threadIdx.x] = m; ls[threadIdx.x] = s;
  __syncthreads();
  for (int st = 128; st > 0; st >>= 1) {
    if (threadIdx.x < st) {
      float4 mm = lm[threadIdx.x], ss = ls[threadIdx.x];
      sm_merge(mm, ss, lm[threadIdx.x + st], ls[threadIdx.x + st]);
      lm[threadIdx.x] = mm; ls[threadIdx.x] = ss;
    }
    __syncthreads();
  }
  if (threadIdx.x == 0) {
    bs_m[blockIdx.x] = lm[0]; bs_s[blockIdx.x] = ls[0];
    __threadfence();                       // release: stats visible device-wide
    islast = (atomicAdd(ticket, 1) == NZBLK - 1);
  }
  __syncthreads();
  if (!islast) return;
  __threadfence();                         // acquire for the combining block
  float4 m2 = make_float4(-1e30f, -1e30f, -1e30f, -1e30f);
  float4 s2 = make_float4(0.f, 0.f, 0.f, 0.f);
  for (int i = threadIdx.x; i < NZBLK; i += 256)
    sm_merge(m2, s2, bs_m[i], bs_s[i]);
  lm[threadIdx.x] = m2; ls[threadIdx.x] = s2;
  __syncthreads();
  for (int st = 128; st > 0; st >>= 1) {
    if (threadIdx.x < st) {
      float4 mm = lm[threadIdx.x], ss = ls[threadIdx.x];
      sm_merge(mm, ss, lm[threadIdx.x + st], ls[threadIdx.x + st]);
      lm[threadIdx.x] = mm; ls[threadIdx.x] = ss;
    }
    __syncthreads();
  }
  if (threadIdx.x == 0) {
    float4 M = lm[0], S = ls[0];
    gms[0] = M.x; gms[1] = M.y; gms[2] = M.z; gms[3] = M.w;
    gms[4] = S.x; gms[5] = S.y; gms[6] = S.z; gms[7] = S.w;
  }
}

// ---------------- normalize --------------------------------------------------
__global__ __launch_bounds__(256) void k_final(const float* __restrict__ z,
                                               const float* __restrict__ gms,
                                               float* __restrict__ out) {
  int p = blockIdx.x * 256 + threadIdx.x;
  if (p < N_PAIRS) {
    float m0 = gms[0], m1 = gms[1], m2 = gms[2], m3 = gms[3];
    float i0 = 1.f / gms[4], i1 = 1.f / gms[5];
    float i2 = 1.f / gms[6], i3 = 1.f / gms[7];
    f4raw zv = __builtin_nontemporal_load((const f4raw*)z + p);
    f4raw o = {expf(zv.x - m0) * i0, expf(zv.y - m1) * i1,
               expf(zv.z - m2) * i2, expf(zv.w - m3) * i3};
    __builtin_nontemporal_store(o, (f4raw*)out + p);
  }
}

extern "C" void kernel_launch(void* const* d_in, const int* in_sizes, int n_in,
                              void* d_out, int out_size, void* d_ws, size_t ws_size,
                              hipStream_t stream) {
  const float* x    = (const float*)d_in[0];
  const float* bank = (const float*)d_in[1];
  const float* W1   = (const float*)d_in[2];
  const float* b1   = (const float*)d_in[3];
  const float* W2   = (const float*)d_in[4];
  const float* b2   = (const float*)d_in[5];
  const float* Wb   = (const float*)d_in[6];
  const float* bb   = (const float*)d_in[7];
  const float* Wf1  = (const float*)d_in[8];
  const float* bf1  = (const float*)d_in[9];
  const float* Wf2  = (const float*)d_in[10];
  const float* bf2  = (const float*)d_in[11];
  const float* Wf3  = (const float*)d_in[12];
  const float* bf3  = (const float*)d_in[13];
  const int* ei     = (const int*)d_in[14];
  const int* node1  = (const int*)d_in[15];
  const int* node2  = (const int*)d_in[16];
  float* out = (float*)d_out;

  char* w = (char*)d_ws;
  size_t off = 0;
  auto take = [&](size_t bytes) -> char* {
    char* p = w + off;
    off = (off + bytes + 255) & ~(size_t)255;
    return p;
  };
  Consts* cst    = (Consts*)take(sizeof(Consts));
  int*    bcnt   = (int*)take((NBUCK + 1) * 4);       // +1: ticket for k_z
  int*    ticket = bcnt + NBUCK;
  float*  dinv   = (float*)take((N_NODES + 1) * 4);   // +1: zero pad row
  int*    rbeg   = (int*)take(N_NODES * 4);
  int*    rend   = (int*)take(N_NODES * 4);
  int*    csr    = (int*)take((size_t)NBUCK * BCAP * 4);
  float*  Xs     = (float*)take((size_t)(N_NODES + 1) * 8 * 4);  // +pad row
  float*  Ys     = (float*)take((size_t)(N_NODES + 1) * 8 * 4);  // +pad row
  float*  dvec   = (float*)take(N_NODES * 4);
  float*  gall   = (float*)take((size_t)(N_NODES + NB_BANK) * 8 * 4);
  // ebuf (build phase) and z (pair phase) have disjoint lifetimes -> share.
  char*   shreg  = take((size_t)NBUCK * BCAP * 4 > (size_t)N_PAIRS * 16
                        ? (size_t)NBUCK * BCAP * 4 : (size_t)N_PAIRS * 16);
  int*    ebuf   = (int*)shreg;
  float*  z      = (float*)shreg;
  float4* bs_m   = (float4*)take((size_t)NZBLK * 16);
  float4* bs_s   = (float4*)take((size_t)NZBLK * 16);
  float*  gms    = (float*)take(32);

  hipMemsetAsync(bcnt, 0, (NBUCK + 1) * 4, stream);   // bcnt + ticket

  // single-pass bucket scatter + (extra block) weight-chain precompute
  k_scatter<<<NSCAT + 1, 1024, 0, stream>>>(ei, bcnt, ebuf, W1, b1, W2, b2,
                                            Wb, bb, Wf1, bf1, Wf2, bf2,
                                            Wf3, bf3, cst);
  // per-bucket: degree/dinv/rbeg/rend + CSR fill + fused Xs compute
  k_degfill_x8<<<NBUCK, 1024, 0, stream>>>(bcnt, ebuf, x, cst,
                                           dinv, rbeg, rend, csr, Xs);
  // propagation (atomic-free float4 half-row gathers, masked unroll-8)
  k_gather1<<<((N_NODES + 1) * 4 + 255) / 256, 256, 0, stream>>>(
      rbeg, rend, csr, dinv, (const float4*)Xs, (float4*)Ys, dvec);
  k_gather2g<<<((N_NODES + NB_BANK) * 4 + 255) / 256, 256, 0, stream>>>(
      rbeg, rend, csr, dinv, (const float4*)Ys, dvec, bank, cst, (float4*)gall);
  // pair phase: z + block stats with last-block combine, then normalize
  k_z<<<NZBLK, 256, 0, stream>>>(node1, node2, gall, z, bs_m, bs_s, ticket, gms);
  k_final<<<NZBLK, 256, 0, stream>>>(z, gms, out);
}

// Round 3
// 246.656 us; speedup vs baseline: 1.0332x; 1.0332x over previous
//
#include <hip/hip_runtime.h>
#include <math.h>

#define N_NODES 100000
#define N_EDGES 1600000
#define NB_BANK 1000
#define N_PAIRS 500000

#define BUCK_SHIFT 9
#define BUCK_NODES 512
#define NBUCK 196            // ceil(N_NODES/512)
#define BCAP 10240           // fixed ebuf/csr stride per bucket (mean 8163 + 22 sigma)
#define EPB 4096             // edges per scatter block (392 blocks: 1.5/CU)
#define NSCAT 391            // ceil(N_EDGES/EPB)
#define NZBLK 1954           // ceil(N_PAIRS/256)
#define SMASK 0x1FFFF        // low 17 bits = src id (N_NODES < 2^17)

struct Consts {
  float C[27*8];    // [P1|P2] : X -> 8 channels
  float Rb[27*8];   // [Wb@Ttop | Wb@Tbot]
  float u[8];       // coefficient of dvec (A-hat * 1)
  float vg[8];      // graph-row constant
  float vb[8];      // bank-row constant
};

// ---- dense weight-chain precompute, runs as the extra block of k_scatter ----
__device__ void precompute_body(
    const float* __restrict__ W1, const float* __restrict__ b1,
    const float* __restrict__ W2, const float* __restrict__ b2,
    const float* __restrict__ Wb, const float* __restrict__ bb,
    const float* __restrict__ Wf1, const float* __restrict__ bf1,
    const float* __restrict__ Wf2, const float* __restrict__ bf2,
    const float* __restrict__ Wf3, const float* __restrict__ bf3,
    Consts* __restrict__ cst) {
  __shared__ float A[40*4];    // Wf2 @ Wf3
  __shared__ float T[100*4];   // Wf1 @ A
  __shared__ float B[60*8];    // W2 @ [Ttop|Tbot]
  __shared__ float cvec[4];
  const int tid = threadIdx.x;
  const int nt = blockDim.x;

  for (int idx = tid; idx < 160; idx += nt) {
    int r = idx >> 2, k = idx & 3;
    float s = 0.f;
    for (int j = 0; j < 20; ++j) s += Wf2[r*20+j] * Wf3[j*4+k];
    A[idx] = s;
  }
  __syncthreads();
  for (int idx = tid; idx < 400; idx += nt) {
    int r = idx >> 2, k = idx & 3;
    float s = 0.f;
    for (int j = 0; j < 40; ++j) s += Wf1[r*40+j] * A[j*4+k];
    T[idx] = s;
  }
  if (tid < 4) {
    float s = bf3[tid];
    for (int j = 0; j < 40; ++j) s += bf1[j] * A[j*4+tid];
    for (int j = 0; j < 20; ++j) s += bf2[j] * Wf3[j*4+tid];
    cvec[tid] = s;
  }
  __syncthreads();
  for (int idx = tid; idx < 480; idx += nt) {
    int r = idx >> 3, k = idx & 7;
    int half = k >> 2, kk = k & 3;
    float s = 0.f;
    for (int j = 0; j < 50; ++j) s += W2[r*50+j] * T[(half*50+j)*4+kk];
    B[idx] = s;
  }
  __syncthreads();
  for (int idx = tid; idx < 456; idx += nt) {
    if (idx < 216) {                       // C = W1 @ B [27,8]
      int r = idx >> 3, k = idx & 7;
      float s = 0.f;
      for (int j = 0; j < 60; ++j) s += W1[r*60+j] * B[j*8+k];
      cst->C[idx] = s;
    } else if (idx < 432) {                // Rb = Wb @ [Ttop|Tbot] [27,8]
      int i2 = idx - 216;
      int r = i2 >> 3, k = i2 & 7, half = k >> 2, kk = k & 3;
      float s = 0.f;
      for (int j = 0; j < 50; ++j) s += Wb[r*50+j] * T[(half*50+j)*4+kk];
      cst->Rb[i2] = s;
    } else if (idx < 440) {                // u = b1 @ B
      int k = idx - 432;
      float s = 0.f;
      for (int j = 0; j < 60; ++j) s += b1[j] * B[j*8+k];
      cst->u[k] = s;
    } else if (idx < 448) {                // vg = b2 @ [Ttop|Tbot] (+c on half 0)
      int k = idx - 440, half = k >> 2, kk = k & 3;
      float s = (half == 0) ? cvec[kk] : 0.f;
      for (int j = 0; j < 50; ++j) s += b2[j] * T[(half*50+j)*4+kk];
      cst->vg[k] = s;
    } else {                               // vb = bb @ [Ttop|Tbot] (+c on half 0)
      int k = idx - 448, half = k >> 2, kk = k & 3;
      float s = (half == 0) ? cvec[kk] : 0.f;
      for (int j = 0; j < 50; ++j) s += bb[j] * T[(half*50+j)*4+kk];
      cst->vb[k] = s;
    }
  }
}

// --- single-pass bucket scatter into fixed-stride ebuf; bcnt[b] -> counts ----
// dst ids register-cached across the two passes; extra block runs precompute.
__global__ __launch_bounds__(1024) void k_scatter(
    const int* __restrict__ ei, int* __restrict__ bcnt, int* __restrict__ ebuf,
    const float* __restrict__ W1, const float* __restrict__ b1,
    const float* __restrict__ W2, const float* __restrict__ b2,
    const float* __restrict__ Wb, const float* __restrict__ bb,
    const float* __restrict__ Wf1, const float* __restrict__ bf1,
    const float* __restrict__ Wf2, const float* __restrict__ bf2,
    const float* __restrict__ Wf3, const float* __restrict__ bf3,
    Consts* __restrict__ cst) {
  if (blockIdx.x == NSCAT) {   // whole-block branch: safe with __syncthreads
    precompute_body(W1, b1, W2, b2, Wb, bb, Wf1, bf1, Wf2, bf2, Wf3, bf3, cst);
    return;
  }
  __shared__ int hist[NBUCK];
  __shared__ int base[NBUCK];
  const int t = threadIdx.x;
  const int e0 = blockIdx.x * EPB;
  int dcache[EPB / 1024];
  if (t < NBUCK) hist[t] = 0;
  __syncthreads();
#pragma unroll
  for (int i = 0; i < EPB / 1024; ++i) {
    int e = e0 + i * 1024 + t;
    int d = (e < N_EDGES) ? ei[N_EDGES + e] : -1;
    dcache[i] = d;
    if (d >= 0) atomicAdd(&hist[d >> BUCK_SHIFT], 1);
  }
  __syncthreads();
  if (t < NBUCK) {
    int h = hist[t];
    base[t] = h ? (t * BCAP + atomicAdd(&bcnt[t], h)) : 0;
    hist[t] = 0;
  }
  __syncthreads();
#pragma unroll
  for (int i = 0; i < EPB / 1024; ++i) {
    int e = e0 + i * 1024 + t;
    int d = dcache[i];
    if (d >= 0) {
      int s = ei[e];
      int b = d >> BUCK_SHIFT;
      int pos = base[b] + atomicAdd(&hist[b], 1);
      ebuf[pos] = ((d & (BUCK_NODES - 1)) << 17) | s;
    }
  }
}

// -- per-bucket: degree -> dinv + rbeg/rend, CSR fill, AND fused Xs compute ---
// (k_x8 folded in: this block owns exactly the 512 nodes whose dinv it just
//  computed; x rows staged in LDS. Also writes the zero pad row at N_NODES
//  used by the masked gather batches.)
__global__ __launch_bounds__(1024) void k_degfill_x8(
    const int* __restrict__ bcnt, const int* __restrict__ ebuf,
    const float* __restrict__ x, const Consts* __restrict__ cst,
    float* __restrict__ dinv, int* __restrict__ rbeg, int* __restrict__ rend,
    int* __restrict__ csr, float* __restrict__ Xs) {
  __shared__ int cnt[BUCK_NODES];
  __shared__ int lcur[BUCK_NODES];
  __shared__ float sdinv[BUCK_NODES];
  __shared__ float xs[BUCK_NODES * 27];     // 55.3 KB (total ~60 KB < 64 KB)
  const int b = blockIdx.x;
  const int t = threadIdx.x;
  if (t < BUCK_NODES) cnt[t] = 0;
  __syncthreads();
  const int beg = b * BCAP, end = beg + bcnt[b];
  for (int j = beg + t; j < end; j += 1024)
    atomicAdd(&cnt[ebuf[j] >> 17], 1);
  // stage x rows for this bucket (independent work, overlaps count pass)
  const int xbase = b * (BUCK_NODES * 27);
  for (int j = t; j < BUCK_NODES * 27; j += 1024) {
    int g = xbase + j;
    xs[j] = (g < N_NODES * 27) ? x[g] : 0.f;
  }
  __syncthreads();
  int v = (t < BUCK_NODES) ? cnt[t] : 0;
  // Hillis-Steele inclusive scan over 512 (threads >=512 idle but hit barriers)
  for (int off = 1; off < BUCK_NODES; off <<= 1) {
    int u = (t < BUCK_NODES && t >= off) ? cnt[t - off] : 0;
    __syncthreads();
    if (t < BUCK_NODES) cnt[t] += u;
    __syncthreads();
  }
  if (t < BUCK_NODES) {
    const int node = (b << BUCK_SHIFT) + t;
    const int excl = beg + cnt[t] - v;   // start within this bucket's csr range
    lcur[t] = excl;
    float dv = (node < N_NODES) ? rsqrtf((float)v + 1.0f) : 0.f;
    sdinv[t] = dv;
    if (node < N_NODES) {
      rbeg[node] = excl;
      rend[node] = excl + v;
      dinv[node] = dv;
    } else if (node == N_NODES) {
      dinv[node] = 0.f;                  // pad row for masked gathers
    }
  }
  __syncthreads();
  for (int j = beg + t; j < end; j += 1024) {
    int code = ebuf[j];
    int pos = atomicAdd(&lcur[code >> 17], 1);
    csr[pos] = code & SMASK;
  }
  // fused Xs = (x @ C) * dinv for this bucket's 512 nodes (+ zero pad row)
  for (int idx = t; idx < BUCK_NODES * 8; idx += 1024) {
    int li = idx >> 3, k = idx & 7;
    int node = (b << BUCK_SHIFT) + li;
    if (node <= N_NODES) {               // node==N_NODES: xs row + sdinv are 0
      float s = 0.f;
      for (int c = 0; c < 27; ++c) s += xs[li*27+c] * cst->C[c*8+k];
      Xs[(size_t)node*8+k] = s * sdinv[li];
    }
  }
}

// ------ gather pass 1: 4-lane teams (2 channel-halves x 2 row-halves) --------
// Fully-masked unroll-8 batches: OOB lanes clamp into csr and redirect the
// payload to the zero pad row N_NODES -> no serial dependent-chain tail.
__global__ __launch_bounds__(256) void k_gather1(
    const int* __restrict__ rbeg, const int* __restrict__ rend,
    const int* __restrict__ csr, const float* __restrict__ dinv,
    const float4* __restrict__ Xs4, float4* __restrict__ Ys4,
    float* __restrict__ dvec) {
  int t = blockIdx.x * 256 + threadIdx.x;
  int d = t >> 2;
  if (d > N_NODES) return;
  int q = t & 1, r = (t >> 1) & 1;       // q: channel half, r: row half
  if (d == N_NODES) {                    // zero pad row for pass-2 masking
    if (r == 0) Ys4[(size_t)d*2+q] = make_float4(0.f, 0.f, 0.f, 0.f);
    return;
  }
  const int beg = rbeg[d], end = rend[d], e1 = end - 1;
  const float nd = dinv[d];
  float ax = 0.f, ay = 0.f, az = 0.f, aw = 0.f, dsum = 0.f;
  for (int j = beg + r; j < end; j += 16) {   // this lane: stride-2 edges
    int k1 = j+2, k2 = j+4, k3 = j+6, k4 = j+8, k5 = j+10, k6 = j+12, k7 = j+14;
    int c0 = csr[j];
    int c1 = csr[k1 < e1 ? k1 : e1];
    int c2 = csr[k2 < e1 ? k2 : e1];
    int c3 = csr[k3 < e1 ? k3 : e1];
    int c4 = csr[k4 < e1 ? k4 : e1];
    int c5 = csr[k5 < e1 ? k5 : e1];
    int c6 = csr[k6 < e1 ? k6 : e1];
    int c7 = csr[k7 < e1 ? k7 : e1];
    int s0 = c0;
    int s1 = (k1 < end) ? c1 : N_NODES;
    int s2 = (k2 < end) ? c2 : N_NODES;
    int s3 = (k3 < end) ? c3 : N_NODES;
    int s4 = (k4 < end) ? c4 : N_NODES;
    int s5 = (k5 < end) ? c5 : N_NODES;
    int s6 = (k6 < end) ? c6 : N_NODES;
    int s7 = (k7 < end) ? c7 : N_NODES;
    float4 a0 = Xs4[(size_t)s0*2+q], a1 = Xs4[(size_t)s1*2+q];
    float4 a2 = Xs4[(size_t)s2*2+q], a3 = Xs4[(size_t)s3*2+q];
    float4 a4 = Xs4[(size_t)s4*2+q], a5 = Xs4[(size_t)s5*2+q];
    float4 a6 = Xs4[(size_t)s6*2+q], a7 = Xs4[(size_t)s7*2+q];
    ax += ((a0.x+a1.x)+(a2.x+a3.x)) + ((a4.x+a5.x)+(a6.x+a7.x));
    ay += ((a0.y+a1.y)+(a2.y+a3.y)) + ((a4.y+a5.y)+(a6.y+a7.y));
    az += ((a0.z+a1.z)+(a2.z+a3.z)) + ((a4.z+a5.z)+(a6.z+a7.z));
    aw += ((a0.w+a1.w)+(a2.w+a3.w)) + ((a4.w+a5.w)+(a6.w+a7.w));
    if (q == 0)
      dsum += ((dinv[s0]+dinv[s1]) + (dinv[s2]+dinv[s3]))
            + ((dinv[s4]+dinv[s5]) + (dinv[s6]+dinv[s7]));
  }
  // combine the two row-halves (lanes differing in bit 1)
  ax += __shfl_xor(ax, 2); ay += __shfl_xor(ay, 2);
  az += __shfl_xor(az, 2); aw += __shfl_xor(aw, 2);
  if (q == 0) dsum += __shfl_xor(dsum, 2);
  if (r == 0) {
    float4 self = Xs4[(size_t)d*2+q];
    float nn = nd * nd;
    Ys4[(size_t)d*2+q] = make_float4(nn*(ax+self.x), nn*(ay+self.y),
                                     nn*(az+self.z), nn*(aw+self.w));
    if (q == 0) dvec[d] = nd * (dsum + nd);   // +nd = self-loop term
  }
}

// ------ gather pass 2 (+bank rows): gall = nd(sum+self) + dvec*u + vg --------
__global__ __launch_bounds__(256) void k_gather2g(
    const int* __restrict__ rbeg, const int* __restrict__ rend,
    const int* __restrict__ csr, const float* __restrict__ dinv,
    const float4* __restrict__ Ys4, const float* __restrict__ dvec,
    const float* __restrict__ bank, const Consts* __restrict__ cst,
    float4* __restrict__ gall4) {
  int t = blockIdx.x * 256 + threadIdx.x;
  int d = t >> 2;
  if (d >= N_NODES + NB_BANK) return;
  int q = t & 1, r = (t >> 1) & 1;
  if (d >= N_NODES) {                    // bank rows: r==0 lanes only
    if (r) return;
    int bk = d - N_NODES;
    int c0 = 4*q;
    float sa = cst->vb[c0],   sb = cst->vb[c0+1];
    float sc = cst->vb[c0+2], sd = cst->vb[c0+3];
    for (int cc = 0; cc < 27; ++cc) {
      float bv = bank[bk*27+cc];
      sa += bv * cst->Rb[cc*8+c0];
      sb += bv * cst->Rb[cc*8+c0+1];
      sc += bv * cst->Rb[cc*8+c0+2];
      sd += bv * cst->Rb[cc*8+c0+3];
    }
    gall4[(size_t)d*2+q] = make_float4(sa, sb, sc, sd);
    return;
  }
  const int beg = rbeg[d], end = rend[d], e1 = end - 1;
  float ax = 0.f, ay = 0.f, az = 0.f, aw = 0.f;
  for (int j = beg + r; j < end; j += 16) {
    int k1 = j+2, k2 = j+4, k3 = j+6, k4 = j+8, k5 = j+10, k6 = j+12, k7 = j+14;
    int c0 = csr[j];
    int c1 = csr[k1 < e1 ? k1 : e1];
    int c2 = csr[k2 < e1 ? k2 : e1];
    int c3 = csr[k3 < e1 ? k3 : e1];
    int c4 = csr[k4 < e1 ? k4 : e1];
    int c5 = csr[k5 < e1 ? k5 : e1];
    int c6 = csr[k6 < e1 ? k6 : e1];
    int c7 = csr[k7 < e1 ? k7 : e1];
    int s0 = c0;
    int s1 = (k1 < end) ? c1 : N_NODES;
    int s2 = (k2 < end) ? c2 : N_NODES;
    int s3 = (k3 < end) ? c3 : N_NODES;
    int s4 = (k4 < end) ? c4 : N_NODES;
    int s5 = (k5 < end) ? c5 : N_NODES;
    int s6 = (k6 < end) ? c6 : N_NODES;
    int s7 = (k7 < end) ? c7 : N_NODES;
    float4 a0 = Ys4[(size_t)s0*2+q], a1 = Ys4[(size_t)s1*2+q];
    float4 a2 = Ys4[(size_t)s2*2+q], a3 = Ys4[(size_t)s3*2+q];
    float4 a4 = Ys4[(size_t)s4*2+q], a5 = Ys4[(size_t)s5*2+q];
    float4 a6 = Ys4[(size_t)s6*2+q], a7 = Ys4[(size_t)s7*2+q];
    ax += ((a0.x+a1.x)+(a2.x+a3.x)) + ((a4.x+a5.x)+(a6.x+a7.x));
    ay += ((a0.y+a1.y)+(a2.y+a3.y)) + ((a4.y+a5.y)+(a6.y+a7.y));
    az += ((a0.z+a1.z)+(a2.z+a3.z)) + ((a4.z+a5.z)+(a6.z+a7.z));
    aw += ((a0.w+a1.w)+(a2.w+a3.w)) + ((a4.w+a5.w)+(a6.w+a7.w));
  }
  ax += __shfl_xor(ax, 2); ay += __shfl_xor(ay, 2);
  az += __shfl_xor(az, 2); aw += __shfl_xor(aw, 2);
  if (r == 0) {
    float4 self = Ys4[(size_t)d*2+q];
    float nd = dinv[d], dv = dvec[d];
    int c0 = 4*q;
    gall4[(size_t)d*2+q] = make_float4(
        nd*(ax+self.x) + dv*cst->u[c0]   + cst->vg[c0],
        nd*(ay+self.y) + dv*cst->u[c0+1] + cst->vg[c0+1],
        nd*(az+self.z) + dv*cst->u[c0+2] + cst->vg[c0+2],
        nd*(aw+self.w) + dv*cst->u[c0+3] + cst->vg[c0+3]);
  }
}

// ---------------- online-softmax merge helper --------------------------------
__device__ inline void sm_merge(float4& m1, float4& s1,
                                const float4 m2, const float4 s2) {
  float4 M;
  M.x = fmaxf(m1.x, m2.x); M.y = fmaxf(m1.y, m2.y);
  M.z = fmaxf(m1.z, m2.z); M.w = fmaxf(m1.w, m2.w);
  s1.x = s1.x * expf(m1.x - M.x) + s2.x * expf(m2.x - M.x);
  s1.y = s1.y * expf(m1.y - M.y) + s2.y * expf(m2.y - M.y);
  s1.z = s1.z * expf(m1.z - M.z) + s2.z * expf(m2.z - M.z);
  s1.w = s1.w * expf(m1.w - M.w) + s2.w * expf(m2.w - M.w);
  m1 = M;
}

// ---- pair gather + z + block stats; LAST block combines -> gms (no k_comb) --
__global__ __launch_bounds__(256) void k_z(const int* __restrict__ node1,
                                           const int* __restrict__ node2,
                                           const float* __restrict__ gall,
                                           float* __restrict__ z,
                                           float4* __restrict__ bs_m,
                                           float4* __restrict__ bs_s,
                                           int* __restrict__ ticket,
                                           float* __restrict__ gms) {
  int p = blockIdx.x * 256 + threadIdx.x;
  float4 m = make_float4(-1e30f, -1e30f, -1e30f, -1e30f);
  float4 s = make_float4(0.f, 0.f, 0.f, 0.f);
  if (p < N_PAIRS) {
    int n1 = node1[p], n2 = node2[p];
    const float4 a = *(const float4*)(gall + (size_t)n1*8);
    const float4 b = *(const float4*)(gall + (size_t)n2*8 + 4);
    float4 zv = make_float4(a.x+b.x, a.y+b.y, a.z+b.z, a.w+b.w);
    ((float4*)z)[p] = zv;
    m = zv; s = make_float4(1.f, 1.f, 1.f, 1.f);
  }
  __shared__ float4 lm[256], ls[256];
  __shared__ int islast;
  lm[threadIdx.x] = m; ls[threadIdx.x] = s;
  __syncthreads();
  for (int st = 128; st > 0; st >>= 1) {
    if (threadIdx.x < st) {
      float4 mm = lm[threadIdx.x], ss = ls[threadIdx.x];
      sm_merge(mm, ss, lm[threadIdx.x + st], ls[threadIdx.x + st]);
      lm[threadIdx.x] = mm; ls[threadIdx.x] = ss;
    }
    __syncthreads();
  }
  if (threadIdx.x == 0) {
    bs_m[blockIdx.x] = lm[0]; bs_s[blockIdx.x] = ls[0];
    __threadfence();                       // release: stats visible device-wide
    islast = (atomicAdd(ticket, 1) == NZBLK - 1);
  }
  __syncthreads();
  if (!islast) return;
  __threadfence();                         // acquire for the combining block
  float4 m2 = make_float4(-1e30f, -1e30f, -1e30f, -1e30f);
  float4 s2 = make_float4(0.f, 0.f, 0.f, 0.f);
  for (int i = threadIdx.x; i < NZBLK; i += 256)
    sm_merge(m2, s2, bs_m[i], bs_s[i]);
  lm[threadIdx.x] = m2; ls[threadIdx.x] = s2;
  __syncthreads();
  for (int st = 128; st > 0; st >>= 1) {
    if (threadIdx.x < st) {
      float4 mm = lm[threadIdx.x], ss = ls[threadIdx.x];
      sm_merge(mm, ss, lm[threadIdx.x + st], ls[threadIdx.x + st]);
      lm[threadIdx.x] = mm; ls[threadIdx.x] = ss;
    }
    __syncthreads();
  }
  if (threadIdx.x == 0) {
    float4 M = lm[0], S = ls[0];
    gms[0] = M.x; gms[1] = M.y; gms[2] = M.z; gms[3] = M.w;
    gms[4] = S.x; gms[5] = S.y; gms[6] = S.z; gms[7] = S.w;
  }
}

// ---------------- normalize --------------------------------------------------
__global__ __launch_bounds__(256) void k_final(const float* __restrict__ z,
                                               const float* __restrict__ gms,
                                               float* __restrict__ out) {
  int p = blockIdx.x * 256 + threadIdx.x;
  if (p < N_PAIRS) {
    float m0 = gms[0], m1 = gms[1], m2 = gms[2], m3 = gms[3];
    float i0 = 1.f / gms[4], i1 = 1.f / gms[5];
    float i2 = 1.f / gms[6], i3 = 1.f / gms[7];
    float4 zv = ((const float4*)z)[p];
    float4 o = make_float4(expf(zv.x - m0) * i0, expf(zv.y - m1) * i1,
                           expf(zv.z - m2) * i2, expf(zv.w - m3) * i3);
    ((float4*)out)[p] = o;
  }
}

extern "C" void kernel_launch(void* const* d_in, const int* in_sizes, int n_in,
                              void* d_out, int out_size, void* d_ws, size_t ws_size,
                              hipStream_t stream) {
  const float* x    = (const float*)d_in[0];
  const float* bank = (const float*)d_in[1];
  const float* W1   = (const float*)d_in[2];
  const float* b1   = (const float*)d_in[3];
  const float* W2   = (const float*)d_in[4];
  const float* b2   = (const float*)d_in[5];
  const float* Wb   = (const float*)d_in[6];
  const float* bb   = (const float*)d_in[7];
  const float* Wf1  = (const float*)d_in[8];
  const float* bf1  = (const float*)d_in[9];
  const float* Wf2  = (const float*)d_in[10];
  const float* bf2  = (const float*)d_in[11];
  const float* Wf3  = (const float*)d_in[12];
  const float* bf3  = (const float*)d_in[13];
  const int* ei     = (const int*)d_in[14];
  const int* node1  = (const int*)d_in[15];
  const int* node2  = (const int*)d_in[16];
  float* out = (float*)d_out;

  char* w = (char*)d_ws;
  size_t off = 0;
  auto take = [&](size_t bytes) -> char* {
    char* p = w + off;
    off = (off + bytes + 255) & ~(size_t)255;
    return p;
  };
  Consts* cst    = (Consts*)take(sizeof(Consts));
  int*    bcnt   = (int*)take((NBUCK + 1) * 4);       // +1: ticket for k_z
  int*    ticket = bcnt + NBUCK;
  float*  dinv   = (float*)take((N_NODES + 1) * 4);   // +1: zero pad row
  int*    rbeg   = (int*)take(N_NODES * 4);
  int*    rend   = (int*)take(N_NODES * 4);
  int*    csr    = (int*)take((size_t)NBUCK * BCAP * 4);
  float*  Xs     = (float*)take((size_t)(N_NODES + 1) * 8 * 4);  // +pad row
  float*  Ys     = (float*)take((size_t)(N_NODES + 1) * 8 * 4);  // +pad row
  float*  dvec   = (float*)take(N_NODES * 4);
  float*  gall   = (float*)take((size_t)(N_NODES + NB_BANK) * 8 * 4);
  // ebuf (build phase) and z (pair phase) have disjoint lifetimes -> share.
  char*   shreg  = take((size_t)NBUCK * BCAP * 4 > (size_t)N_PAIRS * 16
                        ? (size_t)NBUCK * BCAP * 4 : (size_t)N_PAIRS * 16);
  int*    ebuf   = (int*)shreg;
  float*  z      = (float*)shreg;
  float4* bs_m   = (float4*)take((size_t)NZBLK * 16);
  float4* bs_s   = (float4*)take((size_t)NZBLK * 16);
  float*  gms    = (float*)take(32);

  hipMemsetAsync(bcnt, 0, (NBUCK + 1) * 4, stream);   // bcnt + ticket

  // single-pass bucket scatter + (extra block) weight-chain precompute
  k_scatter<<<NSCAT + 1, 1024, 0, stream>>>(ei, bcnt, ebuf, W1, b1, W2, b2,
                                            Wb, bb, Wf1, bf1, Wf2, bf2,
                                            Wf3, bf3, cst);
  // per-bucket: degree/dinv/rbeg/rend + CSR fill + fused Xs compute
  k_degfill_x8<<<NBUCK, 1024, 0, stream>>>(bcnt, ebuf, x, cst,
                                           dinv, rbeg, rend, csr, Xs);
  // propagation (atomic-free float4 half-row gathers, masked unroll-8)
  k_gather1<<<((N_NODES + 1) * 4 + 255) / 256, 256, 0, stream>>>(
      rbeg, rend, csr, dinv, (const float4*)Xs, (float4*)Ys, dvec);
  k_gather2g<<<((N_NODES + NB_BANK) * 4 + 255) / 256, 256, 0, stream>>>(
      rbeg, rend, csr, dinv, (const float4*)Ys, dvec, bank, cst, (float4*)gall);
  // pair phase: z + block stats with last-block combine, then normalize
  k_z<<<NZBLK, 256, 0, stream>>>(node1, node2, gall, z, bs_m, bs_s, ticket, gms);
  k_final<<<NZBLK, 256, 0, stream>>>(z, gms, out);
}

// Round 4
// 204.174 us; speedup vs baseline: 1.2482x; 1.2081x over previous
//
#include <hip/hip_runtime.h>
#include <math.h>

#define N_NODES 100000
#define N_EDGES 1600000
#define NB_BANK 1000
#define N_PAIRS 500000

#define BUCK_SHIFT 9
#define BUCK_NODES 512
#define NBUCK 196            // ceil(N_NODES/512)
#define BCAP 10240           // fixed ebuf/csr stride per bucket (mean 8163 + 22 sigma)
#define EPB 4096             // edges per scatter block (392 blocks: 1.5/CU)
#define NSCAT 391            // ceil(N_EDGES/EPB)
#define NZBLK 1954           // ceil(N_PAIRS/256)
#define SMASK 0x1FFFF        // low 17 bits = src id (N_NODES < 2^17)

struct Consts {
  float C[27*8];    // [P1|P2] : X -> 8 channels
  float Rb[27*8];   // [Wb@Ttop | Wb@Tbot]
  float u[8];       // coefficient of dvec (A-hat * 1)
  float vg[8];      // graph-row constant
  float vb[8];      // bank-row constant
};

// ---- dense weight-chain precompute, runs as the extra block of k_scatter ----
__device__ void precompute_body(
    const float* __restrict__ W1, const float* __restrict__ b1,
    const float* __restrict__ W2, const float* __restrict__ b2,
    const float* __restrict__ Wb, const float* __restrict__ bb,
    const float* __restrict__ Wf1, const float* __restrict__ bf1,
    const float* __restrict__ Wf2, const float* __restrict__ bf2,
    const float* __restrict__ Wf3, const float* __restrict__ bf3,
    Consts* __restrict__ cst) {
  __shared__ float A[40*4];    // Wf2 @ Wf3
  __shared__ float T[100*4];   // Wf1 @ A
  __shared__ float B[60*8];    // W2 @ [Ttop|Tbot]
  __shared__ float cvec[4];
  const int tid = threadIdx.x;
  const int nt = blockDim.x;

  for (int idx = tid; idx < 160; idx += nt) {
    int r = idx >> 2, k = idx & 3;
    float s = 0.f;
    for (int j = 0; j < 20; ++j) s += Wf2[r*20+j] * Wf3[j*4+k];
    A[idx] = s;
  }
  __syncthreads();
  for (int idx = tid; idx < 400; idx += nt) {
    int r = idx >> 2, k = idx & 3;
    float s = 0.f;
    for (int j = 0; j < 40; ++j) s += Wf1[r*40+j] * A[j*4+k];
    T[idx] = s;
  }
  if (tid < 4) {
    float s = bf3[tid];
    for (int j = 0; j < 40; ++j) s += bf1[j] * A[j*4+tid];
    for (int j = 0; j < 20; ++j) s += bf2[j] * Wf3[j*4+tid];
    cvec[tid] = s;
  }
  __syncthreads();
  for (int idx = tid; idx < 480; idx += nt) {
    int r = idx >> 3, k = idx & 7;
    int half = k >> 2, kk = k & 3;
    float s = 0.f;
    for (int j = 0; j < 50; ++j) s += W2[r*50+j] * T[(half*50+j)*4+kk];
    B[idx] = s;
  }
  __syncthreads();
  for (int idx = tid; idx < 456; idx += nt) {
    if (idx < 216) {                       // C = W1 @ B [27,8]
      int r = idx >> 3, k = idx & 7;
      float s = 0.f;
      for (int j = 0; j < 60; ++j) s += W1[r*60+j] * B[j*8+k];
      cst->C[idx] = s;
    } else if (idx < 432) {                // Rb = Wb @ [Ttop|Tbot] [27,8]
      int i2 = idx - 216;
      int r = i2 >> 3, k = i2 & 7, half = k >> 2, kk = k & 3;
      float s = 0.f;
      for (int j = 0; j < 50; ++j) s += Wb[r*50+j] * T[(half*50+j)*4+kk];
      cst->Rb[i2] = s;
    } else if (idx < 440) {                // u = b1 @ B
      int k = idx - 432;
      float s = 0.f;
      for (int j = 0; j < 60; ++j) s += b1[j] * B[j*8+k];
      cst->u[k] = s;
    } else if (idx < 448) {                // vg = b2 @ [Ttop|Tbot] (+c on half 0)
      int k = idx - 440, half = k >> 2, kk = k & 3;
      float s = (half == 0) ? cvec[kk] : 0.f;
      for (int j = 0; j < 50; ++j) s += b2[j] * T[(half*50+j)*4+kk];
      cst->vg[k] = s;
    } else {                               // vb = bb @ [Ttop|Tbot] (+c on half 0)
      int k = idx - 448, half = k >> 2, kk = k & 3;
      float s = (half == 0) ? cvec[kk] : 0.f;
      for (int j = 0; j < 50; ++j) s += bb[j] * T[(half*50+j)*4+kk];
      cst->vb[k] = s;
    }
  }
}

// --- single-pass bucket scatter into fixed-stride ebuf; bcnt[b] -> counts ----
// dst ids register-cached across the two passes; extra block runs precompute.
__global__ __launch_bounds__(1024) void k_scatter(
    const int* __restrict__ ei, int* __restrict__ bcnt, int* __restrict__ ebuf,
    const float* __restrict__ W1, const float* __restrict__ b1,
    const float* __restrict__ W2, const float* __restrict__ b2,
    const float* __restrict__ Wb, const float* __restrict__ bb,
    const float* __restrict__ Wf1, const float* __restrict__ bf1,
    const float* __restrict__ Wf2, const float* __restrict__ bf2,
    const float* __restrict__ Wf3, const float* __restrict__ bf3,
    Consts* __restrict__ cst) {
  if (blockIdx.x == NSCAT) {   // whole-block branch: safe with __syncthreads
    precompute_body(W1, b1, W2, b2, Wb, bb, Wf1, bf1, Wf2, bf2, Wf3, bf3, cst);
    return;
  }
  __shared__ int hist[NBUCK];
  __shared__ int base[NBUCK];
  const int t = threadIdx.x;
  const int e0 = blockIdx.x * EPB;
  int dcache[EPB / 1024];
  if (t < NBUCK) hist[t] = 0;
  __syncthreads();
#pragma unroll
  for (int i = 0; i < EPB / 1024; ++i) {
    int e = e0 + i * 1024 + t;
    int d = (e < N_EDGES) ? ei[N_EDGES + e] : -1;
    dcache[i] = d;
    if (d >= 0) atomicAdd(&hist[d >> BUCK_SHIFT], 1);
  }
  __syncthreads();
  if (t < NBUCK) {
    int h = hist[t];
    base[t] = h ? (t * BCAP + atomicAdd(&bcnt[t], h)) : 0;
    hist[t] = 0;
  }
  __syncthreads();
#pragma unroll
  for (int i = 0; i < EPB / 1024; ++i) {
    int e = e0 + i * 1024 + t;
    int d = dcache[i];
    if (d >= 0) {
      int s = ei[e];
      int b = d >> BUCK_SHIFT;
      int pos = base[b] + atomicAdd(&hist[b], 1);
      ebuf[pos] = ((d & (BUCK_NODES - 1)) << 17) | s;
    }
  }
}

// -- per-bucket: degree -> dinv + rbeg/rend, CSR fill, AND fused Xs compute ---
// (k_x8 folded in: this block owns exactly the 512 nodes whose dinv it just
//  computed; x rows staged in LDS overlapping the count pass.)
__global__ __launch_bounds__(1024) void k_degfill_x8(
    const int* __restrict__ bcnt, const int* __restrict__ ebuf,
    const float* __restrict__ x, const Consts* __restrict__ cst,
    float* __restrict__ dinv, int* __restrict__ rbeg, int* __restrict__ rend,
    int* __restrict__ csr, float* __restrict__ Xs) {
  __shared__ int cnt[BUCK_NODES];
  __shared__ int lcur[BUCK_NODES];
  __shared__ float sdinv[BUCK_NODES];
  __shared__ float xs[BUCK_NODES * 27];     // 55.3 KB (total ~61.4 KB < 64 KB)
  const int b = blockIdx.x;
  const int t = threadIdx.x;
  if (t < BUCK_NODES) cnt[t] = 0;
  __syncthreads();
  const int beg = b * BCAP, end = beg + bcnt[b];
  for (int j = beg + t; j < end; j += 1024)
    atomicAdd(&cnt[ebuf[j] >> 17], 1);
  // stage x rows for this bucket (independent work, overlaps count pass)
  const int xbase = b * (BUCK_NODES * 27);
  for (int j = t; j < BUCK_NODES * 27; j += 1024) {
    int g = xbase + j;
    xs[j] = (g < N_NODES * 27) ? x[g] : 0.f;
  }
  __syncthreads();
  int v = (t < BUCK_NODES) ? cnt[t] : 0;
  // Hillis-Steele inclusive scan over 512 (threads >=512 idle but hit barriers)
  for (int off = 1; off < BUCK_NODES; off <<= 1) {
    int u = (t < BUCK_NODES && t >= off) ? cnt[t - off] : 0;
    __syncthreads();
    if (t < BUCK_NODES) cnt[t] += u;
    __syncthreads();
  }
  if (t < BUCK_NODES) {
    const int node = (b << BUCK_SHIFT) + t;
    const int excl = beg + cnt[t] - v;   // start within this bucket's csr range
    lcur[t] = excl;
    float dv = rsqrtf((float)v + 1.0f);  // +1 self-loop
    sdinv[t] = dv;
    if (node < N_NODES) {
      rbeg[node] = excl;
      rend[node] = excl + v;
      dinv[node] = dv;
    }
  }
  __syncthreads();
  for (int j = beg + t; j < end; j += 1024) {
    int code = ebuf[j];
    int pos = atomicAdd(&lcur[code >> 17], 1);
    csr[pos] = code & SMASK;
  }
  // fused Xs = (x @ C) * dinv for this bucket's 512 nodes
  for (int idx = t; idx < BUCK_NODES * 8; idx += 1024) {
    int li = idx >> 3, k = idx & 7;
    int node = (b << BUCK_SHIFT) + li;
    if (node < N_NODES) {
      float s = 0.f;
      for (int c = 0; c < 27; ++c) s += xs[li*27+c] * cst->C[c*8+k];
      Xs[(size_t)node*8+k] = s * sdinv[li];
    }
  }
}

// ------ gather pass 1 (float2 lanes, unroll-8): Ys = nd^2(sum+self), dvec ----
__global__ __launch_bounds__(256) void k_gather1(const int* __restrict__ rbeg,
                                                 const int* __restrict__ rend,
                                                 const int* __restrict__ csr,
                                                 const float* __restrict__ dinv,
                                                 const float2* __restrict__ Xs2,
                                                 float2* __restrict__ Ys2,
                                                 float* __restrict__ dvec) {
  int t = blockIdx.x * 256 + threadIdx.x;
  int d = t >> 2, q = t & 3;
  if (d >= N_NODES) return;
  const int beg = rbeg[d], end = rend[d];
  const float nd = dinv[d];
  float2 self = Xs2[d*4 + q];
  float ax = self.x, ay = self.y;
  float dsum = nd;                  // self-loop contribution
  int j = beg;
  for (; j + 8 <= end; j += 8) {    // unroll-8: 8 independent loads in flight
    int s0 = csr[j],   s1 = csr[j+1], s2 = csr[j+2], s3 = csr[j+3];
    int s4 = csr[j+4], s5 = csr[j+5], s6 = csr[j+6], s7 = csr[j+7];
    float2 a0 = Xs2[s0*4+q], a1 = Xs2[s1*4+q], a2 = Xs2[s2*4+q], a3 = Xs2[s3*4+q];
    float2 a4 = Xs2[s4*4+q], a5 = Xs2[s5*4+q], a6 = Xs2[s6*4+q], a7 = Xs2[s7*4+q];
    ax += ((a0.x + a1.x) + (a2.x + a3.x)) + ((a4.x + a5.x) + (a6.x + a7.x));
    ay += ((a0.y + a1.y) + (a2.y + a3.y)) + ((a4.y + a5.y) + (a6.y + a7.y));
    if (q == 0)
      dsum += ((dinv[s0] + dinv[s1]) + (dinv[s2] + dinv[s3]))
            + ((dinv[s4] + dinv[s5]) + (dinv[s6] + dinv[s7]));
  }
  for (; j < end; ++j) {
    int s = csr[j];
    float2 a = Xs2[s*4+q];
    ax += a.x; ay += a.y;
    if (q == 0) dsum += dinv[s];
  }
  float nn = nd * nd;
  Ys2[t] = make_float2(nn * ax, nn * ay);   // = n_d * h1 (pre-scaled for pass 2)
  if (q == 0) dvec[d] = nd * dsum;
}

// ------ gather pass 2 (+bank rows): gall = nd(sum+self) + dvec*u + vg --------
__global__ __launch_bounds__(256) void k_gather2g(const int* __restrict__ rbeg,
                                                  const int* __restrict__ rend,
                                                  const int* __restrict__ csr,
                                                  const float* __restrict__ dinv,
                                                  const float2* __restrict__ Ys2,
                                                  const float* __restrict__ dvec,
                                                  const float* __restrict__ bank,
                                                  const Consts* __restrict__ cst,
                                                  float2* __restrict__ gall2) {
  int t = blockIdx.x * 256 + threadIdx.x;
  int d = t >> 2, q = t & 3;
  if (d >= N_NODES + NB_BANK) return;
  int c0 = 2*q, c1 = 2*q + 1;
  if (d >= N_NODES) {               // bank rows
    int bk = d - N_NODES;
    float sx = cst->vb[c0], sy = cst->vb[c1];
    for (int cc = 0; cc < 27; ++cc) {
      float bv = bank[bk*27+cc];
      sx += bv * cst->Rb[cc*8+c0];
      sy += bv * cst->Rb[cc*8+c1];
    }
    gall2[t] = make_float2(sx, sy);
    return;
  }
  const int beg = rbeg[d], end = rend[d];
  float2 self = Ys2[d*4 + q];
  float ax = self.x, ay = self.y;
  int j = beg;
  for (; j + 8 <= end; j += 8) {
    int s0 = csr[j],   s1 = csr[j+1], s2 = csr[j+2], s3 = csr[j+3];
    int s4 = csr[j+4], s5 = csr[j+5], s6 = csr[j+6], s7 = csr[j+7];
    float2 a0 = Ys2[s0*4+q], a1 = Ys2[s1*4+q], a2 = Ys2[s2*4+q], a3 = Ys2[s3*4+q];
    float2 a4 = Ys2[s4*4+q], a5 = Ys2[s5*4+q], a6 = Ys2[s6*4+q], a7 = Ys2[s7*4+q];
    ax += ((a0.x + a1.x) + (a2.x + a3.x)) + ((a4.x + a5.x) + (a6.x + a7.x));
    ay += ((a0.y + a1.y) + (a2.y + a3.y)) + ((a4.y + a5.y) + (a6.y + a7.y));
  }
  for (; j < end; ++j) {
    float2 a = Ys2[csr[j]*4+q];
    ax += a.x; ay += a.y;
  }
  float nd = dinv[d], dv = dvec[d];
  gall2[t] = make_float2(nd * ax + dv * cst->u[c0] + cst->vg[c0],
                         nd * ay + dv * cst->u[c1] + cst->vg[c1]);
}

// ---------------- online-softmax merge helper --------------------------------
__device__ inline void sm_merge(float4& m1, float4& s1,
                                const float4 m2, const float4 s2) {
  float4 M;
  M.x = fmaxf(m1.x, m2.x); M.y = fmaxf(m1.y, m2.y);
  M.z = fmaxf(m1.z, m2.z); M.w = fmaxf(m1.w, m2.w);
  s1.x = s1.x * expf(m1.x - M.x) + s2.x * expf(m2.x - M.x);
  s1.y = s1.y * expf(m1.y - M.y) + s2.y * expf(m2.y - M.y);
  s1.z = s1.z * expf(m1.z - M.z) + s2.z * expf(m2.z - M.z);
  s1.w = s1.w * expf(m1.w - M.w) + s2.w * expf(m2.w - M.w);
  m1 = M;
}

// ---------------- pair gather + z + per-block online (max,sumexp) ------------
__global__ __launch_bounds__(256) void k_z(const int* __restrict__ node1,
                                           const int* __restrict__ node2,
                                           const float* __restrict__ gall,
                                           float* __restrict__ z,
                                           float4* __restrict__ bs_m,
                                           float4* __restrict__ bs_s) {
  int p = blockIdx.x * 256 + threadIdx.x;
  float4 m = make_float4(-1e30f, -1e30f, -1e30f, -1e30f);
  float4 s = make_float4(0.f, 0.f, 0.f, 0.f);
  if (p < N_PAIRS) {
    int n1 = node1[p], n2 = node2[p];
    const float4 a = *(const float4*)(gall + (size_t)n1*8);
    const float4 b = *(const float4*)(gall + (size_t)n2*8 + 4);
    float4 zv = make_float4(a.x+b.x, a.y+b.y, a.z+b.z, a.w+b.w);
    ((float4*)z)[p] = zv;
    m = zv; s = make_float4(1.f, 1.f, 1.f, 1.f);
  }
  __shared__ float4 lm[256], ls[256];
  lm[threadIdx.x] = m; ls[threadIdx.x] = s;
  __syncthreads();
  for (int st = 128; st > 0; st >>= 1) {
    if (threadIdx.x < st) {
      float4 mm = lm[threadIdx.x], ss = ls[threadIdx.x];
      sm_merge(mm, ss, lm[threadIdx.x + st], ls[threadIdx.x + st]);
      lm[threadIdx.x] = mm; ls[threadIdx.x] = ss;
    }
    __syncthreads();
  }
  if (threadIdx.x == 0) { bs_m[blockIdx.x] = lm[0]; bs_s[blockIdx.x] = ls[0]; }
}

// ---------------- combine block stats -> global (m, S) -----------------------
__global__ __launch_bounds__(256) void k_comb(const float4* __restrict__ bs_m,
                                              const float4* __restrict__ bs_s,
                                              float* __restrict__ gms) {
  float4 m = make_float4(-1e30f, -1e30f, -1e30f, -1e30f);
  float4 s = make_float4(0.f, 0.f, 0.f, 0.f);
  for (int i = threadIdx.x; i < NZBLK; i += 256)
    sm_merge(m, s, bs_m[i], bs_s[i]);
  __shared__ float4 lm[256], ls[256];
  lm[threadIdx.x] = m; ls[threadIdx.x] = s;
  __syncthreads();
  for (int st = 128; st > 0; st >>= 1) {
    if (threadIdx.x < st) {
      float4 mm = lm[threadIdx.x], ss = ls[threadIdx.x];
      sm_merge(mm, ss, lm[threadIdx.x + st], ls[threadIdx.x + st]);
      lm[threadIdx.x] = mm; ls[threadIdx.x] = ss;
    }
    __syncthreads();
  }
  if (threadIdx.x == 0) {
    float4 M = lm[0], S = ls[0];
    gms[0] = M.x; gms[1] = M.y; gms[2] = M.z; gms[3] = M.w;
    gms[4] = S.x; gms[5] = S.y; gms[6] = S.z; gms[7] = S.w;
  }
}

// ---------------- normalize --------------------------------------------------
__global__ __launch_bounds__(256) void k_final(const float* __restrict__ z,
                                               const float* __restrict__ gms,
                                               float* __restrict__ out) {
  int p = blockIdx.x * 256 + threadIdx.x;
  if (p < N_PAIRS) {
    float m0 = gms[0], m1 = gms[1], m2 = gms[2], m3 = gms[3];
    float i0 = 1.f / gms[4], i1 = 1.f / gms[5];
    float i2 = 1.f / gms[6], i3 = 1.f / gms[7];
    float4 zv = ((const float4*)z)[p];
    float4 o = make_float4(expf(zv.x - m0) * i0, expf(zv.y - m1) * i1,
                           expf(zv.z - m2) * i2, expf(zv.w - m3) * i3);
    ((float4*)out)[p] = o;
  }
}

extern "C" void kernel_launch(void* const* d_in, const int* in_sizes, int n_in,
                              void* d_out, int out_size, void* d_ws, size_t ws_size,
                              hipStream_t stream) {
  const float* x    = (const float*)d_in[0];
  const float* bank = (const float*)d_in[1];
  const float* W1   = (const float*)d_in[2];
  const float* b1   = (const float*)d_in[3];
  const float* W2   = (const float*)d_in[4];
  const float* b2   = (const float*)d_in[5];
  const float* Wb   = (const float*)d_in[6];
  const float* bb   = (const float*)d_in[7];
  const float* Wf1  = (const float*)d_in[8];
  const float* bf1  = (const float*)d_in[9];
  const float* Wf2  = (const float*)d_in[10];
  const float* bf2  = (const float*)d_in[11];
  const float* Wf3  = (const float*)d_in[12];
  const float* bf3  = (const float*)d_in[13];
  const int* ei     = (const int*)d_in[14];
  const int* node1  = (const int*)d_in[15];
  const int* node2  = (const int*)d_in[16];
  float* out = (float*)d_out;

  char* w = (char*)d_ws;
  size_t off = 0;
  auto take = [&](size_t bytes) -> char* {
    char* p = w + off;
    off = (off + bytes + 255) & ~(size_t)255;
    return p;
  };
  Consts* cst    = (Consts*)take(sizeof(Consts));
  int*    bcnt   = (int*)take(NBUCK * 4);
  float*  dinv   = (float*)take(N_NODES * 4);
  int*    rbeg   = (int*)take(N_NODES * 4);
  int*    rend   = (int*)take(N_NODES * 4);
  int*    csr    = (int*)take((size_t)NBUCK * BCAP * 4);
  float*  Xs     = (float*)take((size_t)N_NODES * 8 * 4);
  float*  Ys     = (float*)take((size_t)N_NODES * 8 * 4);
  float*  dvec   = (float*)take(N_NODES * 4);
  float*  gall   = (float*)take((size_t)(N_NODES + NB_BANK) * 8 * 4);
  // ebuf (build phase) and z (pair phase) have disjoint lifetimes -> share.
  char*   shreg  = take((size_t)NBUCK * BCAP * 4 > (size_t)N_PAIRS * 16
                        ? (size_t)NBUCK * BCAP * 4 : (size_t)N_PAIRS * 16);
  int*    ebuf   = (int*)shreg;
  float*  z      = (float*)shreg;
  float4* bs_m   = (float4*)take((size_t)NZBLK * 16);
  float4* bs_s   = (float4*)take((size_t)NZBLK * 16);
  float*  gms    = (float*)take(32);

  hipMemsetAsync(bcnt, 0, NBUCK * 4, stream);

  // single-pass bucket scatter + (extra block) weight-chain precompute
  k_scatter<<<NSCAT + 1, 1024, 0, stream>>>(ei, bcnt, ebuf, W1, b1, W2, b2,
                                            Wb, bb, Wf1, bf1, Wf2, bf2,
                                            Wf3, bf3, cst);
  // per-bucket: degree/dinv/rbeg/rend + CSR fill + fused Xs compute
  k_degfill_x8<<<NBUCK, 1024, 0, stream>>>(bcnt, ebuf, x, cst,
                                           dinv, rbeg, rend, csr, Xs);
  // propagation (atomic-free float2 gathers, unroll-8)
  k_gather1<<<(N_NODES * 4 + 255) / 256, 256, 0, stream>>>(
      rbeg, rend, csr, dinv, (const float2*)Xs, (float2*)Ys, dvec);
  k_gather2g<<<((N_NODES + NB_BANK) * 4 + 255) / 256, 256, 0, stream>>>(
      rbeg, rend, csr, dinv, (const float2*)Ys, dvec, bank, cst, (float2*)gall);
  // pair phase: z + block stats, single-block combine, normalize
  k_z<<<NZBLK, 256, 0, stream>>>(node1, node2, gall, z, bs_m, bs_s);
  k_comb<<<1, 256, 0, stream>>>(bs_m, bs_s, gms);
  k_final<<<NZBLK, 256, 0, stream>>>(z, gms, out);
}